// Round 13
// baseline (351.258 us; speedup 1.0000x reference)
//
#include <hip/hip_runtime.h>
#include <cmath>

constexpr int NN  = 50000;          // nodes
constexpr int EE  = 800000;         // raw edges
constexpr int E2C = EE + NN;        // edges incl. self loops = 850000

// bucketed counting sort params (round-8 proven)
constexpr int NBUCK = 256;          // dst buckets
constexpr int BW    = 196;          // bucket width: 196*256 = 50176 >= NN
constexpr int EPT   = 8;            // edges per thread (bin)
constexpr int CH    = 256 * EPT;    // 2048 edges per block
constexpr int NB_B  = (E2C + CH - 1) / CH;  // 416 blocks
constexpr int CAP   = 4096;         // per-bucket pairs capacity
constexpr int SCAP  = 5120;         // per-bucket padded sorted capacity
constexpr int G1ALL = (NN + 63) / 64;       // 782 gemm1 blocks
constexpr int G1A   = 391;                  // gemm1 blocks co-run with bin

constexpr float RLN2 = 1.44269504088896340736f;   // 1/ln2

using bf16x8 = __attribute__((ext_vector_type(8))) short;
using f32x4  = __attribute__((ext_vector_type(4))) float;
using u32x4  = __attribute__((ext_vector_type(4))) unsigned int;

// bf16 helpers (storage bf16, math fp32)
__device__ inline unsigned bf16rne(float f) {
    unsigned u = __builtin_bit_cast(unsigned, f);
    return (u + 0x7fffu + ((u >> 16) & 1u)) >> 16;     // round-nearest-even
}
__device__ inline float bflo(unsigned u) { return __builtin_bit_cast(float, u << 16); }
__device__ inline float bfhi(unsigned u) { return __builtin_bit_cast(float, u & 0xffff0000u); }

// ---------------------------------------------------------------------------
// W[k,c] fp32 -> Wt[c,k] bf16 (all three), + zero bcursor, + alpha sentinels
// (-1e30 at node NN), + zero h sentinel rows (PER-GROUP layouts:
// 128-ch buffers are [8 groups][NN+1][16ch]; 32-ch is [4][NN+1][8ch]).
// ---------------------------------------------------------------------------
__global__ __launch_bounds__(256) void cvt_weights(
    const float* __restrict__ W1, const float* __restrict__ W2,
    const float* __restrict__ W3,
    unsigned short* __restrict__ W1t, unsigned short* __restrict__ W2t,
    unsigned short* __restrict__ W3t, int* __restrict__ bcursor,
    float* __restrict__ AS1, float* __restrict__ AS2, float* __restrict__ AS3,
    unsigned short* __restrict__ HA, unsigned short* __restrict__ HB,
    unsigned short* __restrict__ H3)
{
    int g = blockIdx.x * 256 + threadIdx.x;
    if (g < NBUCK) bcursor[g] = 0;
    if (g < 4) { AS1[NN * 4 + g] = -1e30f; AS2[NN * 4 + g] = -1e30f; }
    if (g == 4) AS3[NN] = -1e30f;
    if (g < 128) {   // grouped sentinel rows: group g>>4, ch g&15
        HA[((size_t)(g >> 4) * (NN + 1) + NN) * 16 + (g & 15)] = 0;
        HB[((size_t)(g >> 4) * (NN + 1) + NN) * 16 + (g & 15)] = 0;
    }
    if (g < 32)      // 4 groups x 8 ch
        H3[((size_t)(g >> 3) * (NN + 1) + NN) * 8 + (g & 7)] = 0;

    const float* W; unsigned short* Wt; int cols;
    if (g < 2048)      { W = W1; Wt = W1t; cols = 128; }
    else if (g < 4096) { W = W2; Wt = W2t; cols = 128; g -= 2048; }
    else if (g < 4608) { W = W3; Wt = W3t; cols = 32;  g -= 4096; }
    else return;
    int c  = g / 16;
    int k8 = (g % 16) * 8;
    unsigned up[4];
    #pragma unroll
    for (int j = 0; j < 4; ++j) {
        float a = W[(k8 + 2 * j) * cols + c];
        float b = W[(k8 + 2 * j + 1) * cols + c];
        up[j] = bf16rne(a) | (bf16rne(b) << 16);
    }
    uint4 u; u.x = up[0]; u.y = up[1]; u.z = up[2]; u.w = up[3];
    *(uint4*)(Wt + c * 128 + k8) = u;
}

// ---------------------------------------------------------------------------
// MFMA GEMM body (64 nodes per bid) + fused alpha dots (alpha pre-scaled by
// 1/ln2 for native v_exp_f32 in aggr). GRP_IN: 0 = flat fp32 input (layer1 x);
// 16 = A read from grouped bf16 layout. GRP_OUT: 16 or 8 = h written to
// grouped layout [COLS/GRP_OUT][NN+1][GRP_OUT].
// ---------------------------------------------------------------------------
template<int NT, int NH, bool F32IN, int GRP_OUT>
__device__ inline void gemm_body(
    int bid, const void* __restrict__ inv, const unsigned short* __restrict__ Wt,
    const float* __restrict__ a_s, const float* __restrict__ a_d,
    unsigned short* __restrict__ hout, float* __restrict__ asrc,
    float* __restrict__ adst)
{
    constexpr int COLS = NT * 16;
    constexpr int TPH  = NT / NH;
    const int lane = threadIdx.x & 63;
    const int wave = threadIdx.x >> 6;
    const int m    = lane & 15;
    const int quad = lane >> 4;
    const int n0   = bid * 64 + wave * 16;

    int arow = n0 + m; if (arow >= NN) arow = NN - 1;

    f32x4 acc[NT] = {};
    #pragma unroll
    for (int kq = 0; kq < 4; ++kq) {
        bf16x8 a;
        if constexpr (F32IN) {
            const float* ap = (const float*)inv + (long long)arow * 128 + quad * 8 + kq * 32;
            float4 v0 = *(const float4*)ap;
            float4 v1 = *(const float4*)(ap + 4);
            a[0] = (short)bf16rne(v0.x); a[1] = (short)bf16rne(v0.y);
            a[2] = (short)bf16rne(v0.z); a[3] = (short)bf16rne(v0.w);
            a[4] = (short)bf16rne(v1.x); a[5] = (short)bf16rne(v1.y);
            a[6] = (short)bf16rne(v1.z); a[7] = (short)bf16rne(v1.w);
        } else {
            // grouped-16 input: channels c..c+7 lie inside one 16-ch group
            int c = quad * 8 + kq * 32;
            a = *(const bf16x8*)((const unsigned short*)inv
                    + ((size_t)(c >> 4) * (NN + 1) + arow) * 16 + (c & 15));
        }
        #pragma unroll
        for (int t = 0; t < NT; ++t) {
            bf16x8 b = *(const bf16x8*)(Wt + (t * 16 + m) * 128 + kq * 32 + quad * 8);
            acc[t] = __builtin_amdgcn_mfma_f32_16x16x32_bf16(a, b, acc[t], 0, 0, 0);
        }
    }

    #pragma unroll
    for (int r = 0; r < 4; ++r) {
        int node = n0 + quad * 4 + r;
        if (node < NN) {
            #pragma unroll
            for (int t = 0; t < NT; ++t) {
                int c2 = t * 16 + m;
                if constexpr (GRP_OUT == 16)
                    hout[((size_t)(c2 >> 4) * (NN + 1) + node) * 16 + (c2 & 15)] =
                        (unsigned short)bf16rne(acc[t][r]);
                else
                    hout[((size_t)(c2 >> 3) * (NN + 1) + node) * 8 + (c2 & 7)] =
                        (unsigned short)bf16rne(acc[t][r]);
            }
        }
    }

    float asv[NT], adv[NT];
    #pragma unroll
    for (int t = 0; t < NT; ++t) {
        asv[t] = a_s[t * 16 + m] * RLN2;
        adv[t] = a_d[t * 16 + m] * RLN2;
    }

    #pragma unroll
    for (int r = 0; r < 4; ++r) {
        const int node = n0 + quad * 4 + r;
        #pragma unroll
        for (int hh = 0; hh < NH; ++hh) {
            float ps = 0.f, pd = 0.f;
            #pragma unroll
            for (int q = 0; q < TPH; ++q) {
                int t = hh * TPH + q;
                ps = fmaf(acc[t][r], asv[t], ps);
                pd = fmaf(acc[t][r], adv[t], pd);
            }
            #pragma unroll
            for (int off = 8; off > 0; off >>= 1) {
                ps += __shfl_down(ps, off, 16);
                pd += __shfl_down(pd, off, 16);
            }
            if (m == 0 && node < NN) {
                asrc[node * NH + hh] = ps;
                adst[node * NH + hh] = pd;
            }
        }
    }
}

// ---------------------------------------------------------------------------
// CSR build bodies (round-8 proven). Record: src:16 | dlocal:8 | bucket:8.
// ---------------------------------------------------------------------------
__device__ inline void bin_body(
    int bid, const int* __restrict__ ei, int* __restrict__ bcursor,
    unsigned* __restrict__ pairs)
{
    __shared__ int cnt[NBUCK];
    __shared__ int scanex[NBUCK];
    __shared__ int base[NBUCK];
    __shared__ int cur[NBUCK];
    __shared__ unsigned stage[CH];       // 8 KB

    const int tid = threadIdx.x;
    const long long e0 = (long long)bid * CH;
    cnt[tid] = 0;
    __syncthreads();

    unsigned rec[EPT]; int bk[EPT];
    #pragma unroll
    for (int j = 0; j < EPT; ++j) {
        long long e = e0 + tid + j * 256;
        bool valid = e < E2C;
        int ss = 0, dd = 0;
        if (valid) {
            if (e < EE) { ss = ei[e]; dd = ei[EE + e]; }
            else        { ss = dd = (int)(e - EE); }
        }
        int b = dd / BW;
        bk[j]  = valid ? b : -1;
        rec[j] = (unsigned)ss | ((unsigned)(dd - b * BW) << 16) | ((unsigned)b << 24);
        if (valid) atomicAdd(&cnt[b], 1);
    }
    __syncthreads();

    const int myc = cnt[tid];
    scanex[tid] = myc;
    __syncthreads();
    for (int off = 1; off < NBUCK; off <<= 1) {
        int t = (tid >= off) ? scanex[tid - off] : 0;
        __syncthreads();
        scanex[tid] += t;
        __syncthreads();
    }
    int excl = scanex[tid] - myc;
    __syncthreads();
    scanex[tid] = excl;
    cur[tid]    = excl;
    base[tid]   = atomicAdd(&bcursor[tid], myc);
    __syncthreads();

    #pragma unroll
    for (int j = 0; j < EPT; ++j) {
        if (bk[j] >= 0) {
            int p = atomicAdd(&cur[bk[j]], 1);
            stage[p] = rec[j];
        }
    }
    __syncthreads();

    const int total = (e0 + CH <= E2C) ? CH : (int)(E2C - e0);
    for (int j = tid; j < total; j += 256) {
        unsigned p = stage[j];
        int b = (int)(p >> 24);
        pairs[(size_t)b * CAP + base[b] + (j - scanex[b])] = p;
    }
}

// sort + LPT degree ranks (round-8 single-pass scatter).
__device__ inline void sort_body(
    int b, const int* __restrict__ bcursor, const unsigned* __restrict__ pairs,
    int2* __restrict__ rowp, unsigned short* __restrict__ sorted_src,
    unsigned short* __restrict__ perm)
{
    __shared__ int deg[256];
    __shared__ int scn[256];
    __shared__ int cur[256];
    __shared__ int hist2[64];
    __shared__ int scn2[64];
    __shared__ int cur2[64];
    const int n0 = b * BW;
    const int n1 = (n0 + BW < NN) ? n0 + BW : NN;
    const int nloc = n1 - n0;
    const int tid = threadIdx.x;
    const int mycnt = bcursor[b];
    const unsigned* seg = pairs + (size_t)b * CAP;
    const int base = b * SCAP;

    deg[tid] = 0;
    if (tid < 64) hist2[tid] = 0;
    __syncthreads();
    for (int i = tid; i < mycnt; i += 256)
        atomicAdd(&deg[(seg[i] >> 16) & 0xff], 1);
    __syncthreads();

    const int pv = (deg[tid] + 3) & ~3;            // padded degree
    int it = pv >> 2; if (it > 63) it = 63;
    it = 63 - it;                                  // descending-degree key (LPT)
    scn[tid] = pv;
    if (tid < nloc) atomicAdd(&hist2[it], 1);
    __syncthreads();
    for (int off = 1; off < 256; off <<= 1) {
        int t = (tid >= off) ? scn[tid - off] : 0;
        __syncthreads();
        scn[tid] += t;
        __syncthreads();
    }
    if (tid < 64) scn2[tid] = hist2[tid];
    __syncthreads();
    for (int off = 1; off < 64; off <<= 1) {
        int t = (tid >= off && tid < 64) ? scn2[tid - off] : 0;
        __syncthreads();
        if (tid < 64) scn2[tid] += t;
        __syncthreads();
    }
    if (tid < 64) cur2[tid] = scn2[tid] - hist2[tid];
    __syncthreads();

    const int totalp = scn[255];
    const int pexcl  = scn[tid] - pv;
    cur[tid] = base + pexcl;
    if (tid < nloc) {
        int rank = atomicAdd(&cur2[it], 1);        // degree-sorted local rank
        perm[n0 + rank] = (unsigned short)(n0 + tid);
        rowp[n0 + rank] = make_int2(base + pexcl, base + pexcl + pv);
    }
    __syncthreads();

    int lim = totalp + 8; if (lim > SCAP) lim = SCAP;
    for (int i = tid; i < lim; i += 256)
        sorted_src[base + i] = (unsigned short)NN;
    if (b == NBUCK - 1 && tid < 8)
        sorted_src[NBUCK * SCAP + tid] = (unsigned short)NN;
    __syncthreads();
    for (int i = tid; i < mycnt; i += 256) {
        unsigned p = seg[i];
        int pos = atomicAdd(&cur[(p >> 16) & 0xff], 1);
        sorted_src[pos] = (unsigned short)(p & 0xffff);
    }
}

// ---------------------------------------------------------------------------
// Overlap dispatches: [bin || gemm1 first half], [sort || gemm1 second half]
// ---------------------------------------------------------------------------
__global__ __launch_bounds__(256) void bin_gemm(
    const int* __restrict__ ei, int* __restrict__ bcursor,
    unsigned* __restrict__ pairs,
    const float* __restrict__ x, const unsigned short* __restrict__ Wt,
    const float* __restrict__ a_s, const float* __restrict__ a_d,
    unsigned short* __restrict__ hout, float* __restrict__ asrc,
    float* __restrict__ adst)
{
    if (blockIdx.x < NB_B)
        bin_body(blockIdx.x, ei, bcursor, pairs);
    else
        gemm_body<8, 4, true, 16>(blockIdx.x - NB_B, x, Wt, a_s, a_d,
                                  hout, asrc, adst);
}

__global__ __launch_bounds__(256) void sort_gemm(
    const int* __restrict__ bcursor, const unsigned* __restrict__ pairs,
    int2* __restrict__ rowp, unsigned short* __restrict__ sorted_src,
    unsigned short* __restrict__ perm,
    const float* __restrict__ x, const unsigned short* __restrict__ Wt,
    const float* __restrict__ a_s, const float* __restrict__ a_d,
    unsigned short* __restrict__ hout, float* __restrict__ asrc,
    float* __restrict__ adst)
{
    if (blockIdx.x < NBUCK)
        sort_body(blockIdx.x, bcursor, pairs, rowp, sorted_src, perm);
    else
        gemm_body<8, 4, true, 16>(blockIdx.x - NBUCK + G1A, x, Wt, a_s, a_d,
                                  hout, asrc, adst);
}

// standalone GEMM wrappers (layers 2 and 3, grouped in/out)
__global__ __launch_bounds__(256) void gemm_l2(
    const unsigned short* __restrict__ hin, const unsigned short* __restrict__ Wt,
    const float* __restrict__ a_s, const float* __restrict__ a_d,
    unsigned short* __restrict__ hout, float* __restrict__ asrc,
    float* __restrict__ adst)
{
    gemm_body<8, 4, false, 16>(blockIdx.x, hin, Wt, a_s, a_d, hout, asrc, adst);
}

__global__ __launch_bounds__(256) void gemm_l3(
    const unsigned short* __restrict__ hin, const unsigned short* __restrict__ Wt,
    const float* __restrict__ a_s, const float* __restrict__ a_d,
    unsigned short* __restrict__ hout, float* __restrict__ asrc,
    float* __restrict__ adst)
{
    gemm_body<2, 1, false, 8>(blockIdx.x, hin, Wt, a_s, a_d, hout, asrc, adst);
}

// ---------------------------------------------------------------------------
// Aggregation core over [b0, e0): padded mask-free 4-deep batches, index
// prefetch; pads -> sentinel node NN. asrc pre-scaled by 1/ln2:
// w = v_exp_f32(leaky(a+d)) == exp(orig). hp points at this lane's 8-ch
// slice; row stride = USTR uints (COLS/2).
// ---------------------------------------------------------------------------
template<int COLS, int NH>
__device__ inline void aggr_range(
    int b0, int e0, int head, float ad,
    const unsigned short* __restrict__ sorted_src,
    const uint* __restrict__ hp,
    const float* __restrict__ asrc,
    float num[8], float& den)
{
    constexpr int USTR = COLS / 2;            // uints per row
    ushort4 sv = *(const ushort4*)&sorted_src[b0];
    for (int i = b0; i < e0; i += 4) {
        ushort4 nx = *(const ushort4*)&sorted_src[i + 4];   // slack sentinel-filled
        const int s[4] = {sv.x, sv.y, sv.z, sv.w};
        float a[4];
        uint4 Hv[4];
        #pragma unroll
        for (int j = 0; j < 4; ++j) a[j] = asrc[s[j] * NH + head];
        #pragma unroll
        for (int j = 0; j < 4; ++j)
            Hv[j] = *(const uint4*)&hp[(long long)s[j] * USTR];
        #pragma unroll
        for (int j = 0; j < 4; ++j) {
            float l = a[j] + ad; l = l > 0.f ? l : 0.2f * l;
            float w;
            asm("v_exp_f32 %0, %1" : "=v"(w) : "v"(l));     // 2^l
            den += w;
            num[0] = fmaf(w, bflo(Hv[j].x), num[0]); num[1] = fmaf(w, bfhi(Hv[j].x), num[1]);
            num[2] = fmaf(w, bflo(Hv[j].y), num[2]); num[3] = fmaf(w, bfhi(Hv[j].y), num[3]);
            num[4] = fmaf(w, bflo(Hv[j].z), num[4]); num[5] = fmaf(w, bfhi(Hv[j].z), num[5]);
            num[6] = fmaf(w, bflo(Hv[j].w), num[6]); num[7] = fmaf(w, bfhi(Hv[j].w), num[7]);
        }
        sv = nx;
    }
}

// ---------------------------------------------------------------------------
// CHANNEL-SLICED aggregation (128-ch layers): block (g = blockIdx%8,
// i = blockIdx/8) aggregates ONLY group g's 16 channels for 128 nodes
// (2 lanes/node). With round-robin block->XCD dispatch, each XCD touches
// only its group's slice of h (16 ch x (NN+1) = 1.6 MB, L2-resident) —
// compulsory HBM fetch drops from 8x12MB to ~1x12MB total. Output stores
// are non-temporal to protect slice residency in L2.
// ---------------------------------------------------------------------------
__global__ __launch_bounds__(256) void aggr_slice128(
    const unsigned short* __restrict__ perm,
    const int2* __restrict__ rowp, const unsigned short* __restrict__ sorted_src,
    const unsigned short* __restrict__ hin,      // [8][NN+1][16] bf16
    const float* __restrict__ asrc, const float* __restrict__ adst,
    const float* __restrict__ bias,
    unsigned short* __restrict__ outg)           // [8][NN+1][16] bf16
{
    const int g    = blockIdx.x & 7;             // channel group -> XCD
    const int ib   = blockIdx.x >> 3;
    const int tid  = threadIdx.x;
    const int ln   = tid >> 1;                   // local node 0..127
    const int half = tid & 1;                    // 8-ch half of the group
    const int rk   = ib * 128 + ln;
    if (rk >= NN) return;
    const int d    = perm[rk];
    const int head = g >> 1;                     // 32 ch per head
    const float ad = adst[d * 4 + head];
    const uint* hp = (const uint*)hin + (size_t)g * (NN + 1) * 8 + half * 4;
    const int2 be  = rowp[rk];

    float num[8] = {};
    float den = 0.f;
    aggr_range<16, 4>(be.x, be.y, head, ad, sorted_src, hp, asrc, num, den);

    float inv = 1.f / (den + 1e-16f);
    const int cc = g * 16 + half * 8;            // absolute channel base
    float v[8];
    #pragma unroll
    for (int j = 0; j < 8; ++j) {
        v[j] = num[j] * inv + bias[cc + j];
        v[j] = v[j] > 0.f ? v[j] : expm1f(v[j]);      // ELU
    }
    u32x4 u;
    u[0] = bf16rne(v[0]) | (bf16rne(v[1]) << 16);
    u[1] = bf16rne(v[2]) | (bf16rne(v[3]) << 16);
    u[2] = bf16rne(v[4]) | (bf16rne(v[5]) << 16);
    u[3] = bf16rne(v[6]) | (bf16rne(v[7]) << 16);
    __builtin_nontemporal_store(
        u, (u32x4*)(outg + ((size_t)g * (NN + 1) + d) * 16 + half * 8));
}

// ---------------------------------------------------------------------------
// CHANNEL-SLICED final aggregation (32-ch layer, no ELU, fp32 out):
// 4 groups x 8 ch, 1 lane/node, 256 nodes/block. g = blockIdx%4.
// ---------------------------------------------------------------------------
__global__ __launch_bounds__(256) void aggr_final_g(
    const unsigned short* __restrict__ perm,
    const int2* __restrict__ rowp, const unsigned short* __restrict__ sorted_src,
    const unsigned short* __restrict__ hin,      // [4][NN+1][8] bf16
    const float* __restrict__ asrc, const float* __restrict__ adst,
    const float* __restrict__ bias, float* __restrict__ out)
{
    const int g  = blockIdx.x & 3;
    const int ib = blockIdx.x >> 2;
    const int rk = ib * 256 + threadIdx.x;
    if (rk >= NN) return;
    const int d  = perm[rk];
    const float ad = adst[d];
    const uint* hp = (const uint*)hin + (size_t)g * (NN + 1) * 4;
    const int2 be  = rowp[rk];

    float num[8] = {};
    float den = 0.f;
    aggr_range<8, 1>(be.x, be.y, 0, ad, sorted_src, hp, asrc, num, den);

    float inv = 1.f / (den + 1e-16f);
    const int cc = g * 8;
    float v[8];
    #pragma unroll
    for (int j = 0; j < 8; ++j) v[j] = num[j] * inv + bias[cc + j];
    float* op = out + (long long)d * 32 + cc;
    *(float4*)(op)     = make_float4(v[0], v[1], v[2], v[3]);
    *(float4*)(op + 4) = make_float4(v[4], v[5], v[6], v[7]);
}

// ---------------------------------------------------------------------------
extern "C" void kernel_launch(void* const* d_in, const int* in_sizes, int n_in,
                              void* d_out, int out_size, void* d_ws, size_t ws_size,
                              hipStream_t stream)
{
    const float* x   = (const float*)d_in[0];
    const int*   ei  = (const int*)  d_in[1];
    const float* W1  = (const float*)d_in[2];
    const float* as1 = (const float*)d_in[3];
    const float* ad1 = (const float*)d_in[4];
    const float* b1  = (const float*)d_in[5];
    const float* W2  = (const float*)d_in[6];
    const float* as2 = (const float*)d_in[7];
    const float* ad2 = (const float*)d_in[8];
    const float* b2  = (const float*)d_in[9];
    const float* W3  = (const float*)d_in[10];
    const float* as3 = (const float*)d_in[11];
    const float* ad3 = (const float*)d_in[12];
    const float* b3  = (const float*)d_in[13];
    float* out = (float*)d_out;

    // workspace: HA/HB = (NN+1)*128 bf16 grouped [8][NN+1][16];
    // H3 = (NN+1)*32 grouped [4][NN+1][8]. Ping-pong:
    // gemm1: x -> HA; aggr1: HA -> HB; gemm2: HB -> HA; aggr2: HA -> HB;
    // gemm3: HB -> H3; aggr3: H3 -> out.
    unsigned short* HA  = (unsigned short*)d_ws;          // (N+1)*128 bf16
    unsigned short* HB  = HA + (size_t)(NN + 1) * 128;    // (N+1)*128 bf16
    unsigned short* H3  = HB + (size_t)(NN + 1) * 128;    // (N+1)*32 bf16
    unsigned short* W1t = H3 + (size_t)(NN + 1) * 32;     // 128*128 bf16
    unsigned short* W2t = W1t + 128 * 128;
    unsigned short* W3t = W2t + 128 * 128;                // 32*128
    float* AS1 = (float*)(W3t + 32 * 128);                // (N+1)*4
    float* AD1 = AS1 + (size_t)(NN + 1) * 4;              // N*4
    float* AS2 = AD1 + (size_t)NN * 4;                    // (N+1)*4
    float* AD2 = AS2 + (size_t)(NN + 1) * 4;              // N*4
    float* AS3 = AD2 + (size_t)NN * 4;                    // (N+1)
    float* AD3 = AS3 + (size_t)(NN + 1);                  // N
    int2* rowp = (int2*)(AD3 + NN);                       // NN int2 (rank-indexed)
    unsigned short* sorted = (unsigned short*)(rowp + NN);         // NBUCK*SCAP+8
    int* bcursor = (int*)(sorted + (size_t)NBUCK * SCAP + 8);      // NBUCK
    unsigned short* perm = (unsigned short*)(bcursor + NBUCK);     // NN u16
    size_t off = ((size_t)(perm + NN) - (size_t)d_ws + 15) & ~(size_t)15;
    unsigned* pairs = (unsigned*)((char*)d_ws + off);     // NBUCK*CAP u32 (4 MB)

    const int gCvtW  = (4608 + 255) / 256;               // 18
    const int gBinG  = NB_B + G1A;                       // 416 + 391
    const int gSortG = NBUCK + (G1ALL - G1A);            // 256 + 391
    const int gGemm  = G1ALL;                            // 782
    const int gAggrS = 8 * ((NN + 127) / 128);           // 3128
    const int gAggrF = 4 * ((NN + 255) / 256);           // 784

    // 1) weights + sentinels + cursor zeroing
    cvt_weights<<<gCvtW, 256, 0, stream>>>(W1, W2, W3, W1t, W2t, W3t, bcursor,
                                           AS1, AS2, AS3, HA, HB, H3);
    // 2) edge binning || layer-1 GEMM (first half) -> HA grouped
    bin_gemm<<<gBinG, 256, 0, stream>>>(ei, bcursor, pairs,
                                        x, W1t, as1, ad1, HA, AS1, AD1);
    // 3) CSR sort (+LPT ranks) || layer-1 GEMM (second half)
    sort_gemm<<<gSortG, 256, 0, stream>>>(bcursor, pairs, rowp, sorted, perm,
                                          x, W1t, as1, ad1, HA, AS1, AD1);
    // 4) aggr layer 1 (channel-sliced, XCD-affine): HA -> HB
    aggr_slice128<<<gAggrS, 256, 0, stream>>>(
        perm, rowp, sorted, HA, AS1, AD1, b1, HB);
    // 5) GEMM layer 2: HB -> HA (+AS2/AD2)
    gemm_l2<<<gGemm, 256, 0, stream>>>(HB, W2t, as2, ad2, HA, AS2, AD2);
    // 6) aggr layer 2: HA -> HB
    aggr_slice128<<<gAggrS, 256, 0, stream>>>(
        perm, rowp, sorted, HA, AS2, AD2, b2, HB);
    // 7) GEMM layer 3: HB -> H3 (+AS3/AD3)
    gemm_l3<<<gGemm, 256, 0, stream>>>(HB, W3t, as3, ad3, H3, AS3, AD3);
    // 8) final aggr (channel-sliced): H3 -> out
    aggr_final_g<<<gAggrF, 256, 0, stream>>>(
        perm, rowp, sorted, H3, AS3, AD3, b3, out);
}

// Round 14
// 288.647 us; speedup vs baseline: 1.2169x; 1.2169x over previous
//
#include <hip/hip_runtime.h>
#include <cmath>

constexpr int NN  = 50000;          // nodes
constexpr int EE  = 800000;         // raw edges
constexpr int E2C = EE + NN;        // edges incl. self loops = 850000

// bucketed counting sort params (round-8 proven)
constexpr int NBUCK = 256;          // dst buckets
constexpr int BW    = 196;          // bucket width: 196*256 = 50176 >= NN
constexpr int EPT   = 8;            // edges per thread (bin)
constexpr int CH    = 256 * EPT;    // 2048 edges per block
constexpr int NB_B  = (E2C + CH - 1) / CH;  // 416 blocks
constexpr int CAP   = 4096;         // per-bucket pairs capacity
constexpr int SCAP  = 5120;         // per-bucket padded sorted capacity
constexpr int G1ALL = (NN + 63) / 64;       // 782 gemm1 blocks
constexpr int G1A   = 391;                  // gemm1 blocks co-run with bin

constexpr float RLN2 = 1.44269504088896340736f;   // 1/ln2

using bf16x8 = __attribute__((ext_vector_type(8))) short;
using f32x4  = __attribute__((ext_vector_type(4))) float;
using u32x4  = __attribute__((ext_vector_type(4))) unsigned int;

// bf16 helpers (storage bf16, math fp32)
__device__ inline unsigned bf16rne(float f) {
    unsigned u = __builtin_bit_cast(unsigned, f);
    return (u + 0x7fffu + ((u >> 16) & 1u)) >> 16;     // round-nearest-even
}
__device__ inline float bflo(unsigned u) { return __builtin_bit_cast(float, u << 16); }
__device__ inline float bfhi(unsigned u) { return __builtin_bit_cast(float, u & 0xffff0000u); }

// ---------------------------------------------------------------------------
// W[k,c] fp32 -> Wt[c,k] bf16 (all three), + zero bcursor, + alpha sentinels
// (-1e30 at node NN), + zero h sentinel rows. 128-ch h buffers are GROUPED
// [4 groups][NN+1][32ch] (64-B rows = 1 cache line: 4 line-touches/edge,
// same as flat 256-B rows, but each XCD's group slice is L2-resident).
// H3 is FLAT (NN+1)*32.
// ---------------------------------------------------------------------------
__global__ __launch_bounds__(256) void cvt_weights(
    const float* __restrict__ W1, const float* __restrict__ W2,
    const float* __restrict__ W3,
    unsigned short* __restrict__ W1t, unsigned short* __restrict__ W2t,
    unsigned short* __restrict__ W3t, int* __restrict__ bcursor,
    float* __restrict__ AS1, float* __restrict__ AS2, float* __restrict__ AS3,
    unsigned short* __restrict__ HA, unsigned short* __restrict__ HB,
    unsigned short* __restrict__ H3)
{
    int g = blockIdx.x * 256 + threadIdx.x;
    if (g < NBUCK) bcursor[g] = 0;
    if (g < 4) { AS1[NN * 4 + g] = -1e30f; AS2[NN * 4 + g] = -1e30f; }
    if (g == 4) AS3[NN] = -1e30f;
    if (g < 128) {   // grouped sentinel rows: group g>>5, ch g&31
        HA[((size_t)(g >> 5) * (NN + 1) + NN) * 32 + (g & 31)] = 0;
        HB[((size_t)(g >> 5) * (NN + 1) + NN) * 32 + (g & 31)] = 0;
    }
    if (g < 32) H3[(size_t)NN * 32 + g] = 0;     // flat sentinel row

    const float* W; unsigned short* Wt; int cols;
    if (g < 2048)      { W = W1; Wt = W1t; cols = 128; }
    else if (g < 4096) { W = W2; Wt = W2t; cols = 128; g -= 2048; }
    else if (g < 4608) { W = W3; Wt = W3t; cols = 32;  g -= 4096; }
    else return;
    int c  = g / 16;
    int k8 = (g % 16) * 8;
    unsigned up[4];
    #pragma unroll
    for (int j = 0; j < 4; ++j) {
        float a = W[(k8 + 2 * j) * cols + c];
        float b = W[(k8 + 2 * j + 1) * cols + c];
        up[j] = bf16rne(a) | (bf16rne(b) << 16);
    }
    uint4 u; u.x = up[0]; u.y = up[1]; u.z = up[2]; u.w = up[3];
    *(uint4*)(Wt + c * 128 + k8) = u;
}

// ---------------------------------------------------------------------------
// MFMA GEMM body (64 nodes per bid) + fused alpha dots (alpha pre-scaled by
// 1/ln2 for native v_exp_f32 in aggr). F32IN: flat fp32 input (layer1 x);
// else input read from grouped-32 bf16 layout. GRP_OUT: 32 = grouped-32
// output layout; 0 = flat COLS layout.
// ---------------------------------------------------------------------------
template<int NT, int NH, bool F32IN, int GRP_OUT>
__device__ inline void gemm_body(
    int bid, const void* __restrict__ inv, const unsigned short* __restrict__ Wt,
    const float* __restrict__ a_s, const float* __restrict__ a_d,
    unsigned short* __restrict__ hout, float* __restrict__ asrc,
    float* __restrict__ adst)
{
    constexpr int COLS = NT * 16;
    constexpr int TPH  = NT / NH;
    const int lane = threadIdx.x & 63;
    const int wave = threadIdx.x >> 6;
    const int m    = lane & 15;
    const int quad = lane >> 4;
    const int n0   = bid * 64 + wave * 16;

    int arow = n0 + m; if (arow >= NN) arow = NN - 1;

    f32x4 acc[NT] = {};
    #pragma unroll
    for (int kq = 0; kq < 4; ++kq) {
        bf16x8 a;
        if constexpr (F32IN) {
            const float* ap = (const float*)inv + (long long)arow * 128 + quad * 8 + kq * 32;
            float4 v0 = *(const float4*)ap;
            float4 v1 = *(const float4*)(ap + 4);
            a[0] = (short)bf16rne(v0.x); a[1] = (short)bf16rne(v0.y);
            a[2] = (short)bf16rne(v0.z); a[3] = (short)bf16rne(v0.w);
            a[4] = (short)bf16rne(v1.x); a[5] = (short)bf16rne(v1.y);
            a[6] = (short)bf16rne(v1.z); a[7] = (short)bf16rne(v1.w);
        } else {
            // grouped-32 input: channels c..c+7 lie inside one 32-ch group
            int c = quad * 8 + kq * 32;
            a = *(const bf16x8*)((const unsigned short*)inv
                    + ((size_t)(c >> 5) * (NN + 1) + arow) * 32 + (c & 31));
        }
        #pragma unroll
        for (int t = 0; t < NT; ++t) {
            bf16x8 b = *(const bf16x8*)(Wt + (t * 16 + m) * 128 + kq * 32 + quad * 8);
            acc[t] = __builtin_amdgcn_mfma_f32_16x16x32_bf16(a, b, acc[t], 0, 0, 0);
        }
    }

    #pragma unroll
    for (int r = 0; r < 4; ++r) {
        int node = n0 + quad * 4 + r;
        if (node < NN) {
            #pragma unroll
            for (int t = 0; t < NT; ++t) {
                int c2 = t * 16 + m;
                if constexpr (GRP_OUT == 32)
                    hout[((size_t)(c2 >> 5) * (NN + 1) + node) * 32 + (c2 & 31)] =
                        (unsigned short)bf16rne(acc[t][r]);
                else
                    hout[(size_t)node * COLS + c2] =
                        (unsigned short)bf16rne(acc[t][r]);
            }
        }
    }

    float asv[NT], adv[NT];
    #pragma unroll
    for (int t = 0; t < NT; ++t) {
        asv[t] = a_s[t * 16 + m] * RLN2;
        adv[t] = a_d[t * 16 + m] * RLN2;
    }

    #pragma unroll
    for (int r = 0; r < 4; ++r) {
        const int node = n0 + quad * 4 + r;
        #pragma unroll
        for (int hh = 0; hh < NH; ++hh) {
            float ps = 0.f, pd = 0.f;
            #pragma unroll
            for (int q = 0; q < TPH; ++q) {
                int t = hh * TPH + q;
                ps = fmaf(acc[t][r], asv[t], ps);
                pd = fmaf(acc[t][r], adv[t], pd);
            }
            #pragma unroll
            for (int off = 8; off > 0; off >>= 1) {
                ps += __shfl_down(ps, off, 16);
                pd += __shfl_down(pd, off, 16);
            }
            if (m == 0 && node < NN) {
                asrc[node * NH + hh] = ps;
                adst[node * NH + hh] = pd;
            }
        }
    }
}

// ---------------------------------------------------------------------------
// CSR build bodies (round-8 proven). Record: src:16 | dlocal:8 | bucket:8.
// ---------------------------------------------------------------------------
__device__ inline void bin_body(
    int bid, const int* __restrict__ ei, int* __restrict__ bcursor,
    unsigned* __restrict__ pairs)
{
    __shared__ int cnt[NBUCK];
    __shared__ int scanex[NBUCK];
    __shared__ int base[NBUCK];
    __shared__ int cur[NBUCK];
    __shared__ unsigned stage[CH];       // 8 KB

    const int tid = threadIdx.x;
    const long long e0 = (long long)bid * CH;
    cnt[tid] = 0;
    __syncthreads();

    unsigned rec[EPT]; int bk[EPT];
    #pragma unroll
    for (int j = 0; j < EPT; ++j) {
        long long e = e0 + tid + j * 256;
        bool valid = e < E2C;
        int ss = 0, dd = 0;
        if (valid) {
            if (e < EE) { ss = ei[e]; dd = ei[EE + e]; }
            else        { ss = dd = (int)(e - EE); }
        }
        int b = dd / BW;
        bk[j]  = valid ? b : -1;
        rec[j] = (unsigned)ss | ((unsigned)(dd - b * BW) << 16) | ((unsigned)b << 24);
        if (valid) atomicAdd(&cnt[b], 1);
    }
    __syncthreads();

    const int myc = cnt[tid];
    scanex[tid] = myc;
    __syncthreads();
    for (int off = 1; off < NBUCK; off <<= 1) {
        int t = (tid >= off) ? scanex[tid - off] : 0;
        __syncthreads();
        scanex[tid] += t;
        __syncthreads();
    }
    int excl = scanex[tid] - myc;
    __syncthreads();
    scanex[tid] = excl;
    cur[tid]    = excl;
    base[tid]   = atomicAdd(&bcursor[tid], myc);
    __syncthreads();

    #pragma unroll
    for (int j = 0; j < EPT; ++j) {
        if (bk[j] >= 0) {
            int p = atomicAdd(&cur[bk[j]], 1);
            stage[p] = rec[j];
        }
    }
    __syncthreads();

    const int total = (e0 + CH <= E2C) ? CH : (int)(E2C - e0);
    for (int j = tid; j < total; j += 256) {
        unsigned p = stage[j];
        int b = (int)(p >> 24);
        pairs[(size_t)b * CAP + base[b] + (j - scanex[b])] = p;
    }
}

// sort + LPT degree ranks (round-8 single-pass scatter).
__device__ inline void sort_body(
    int b, const int* __restrict__ bcursor, const unsigned* __restrict__ pairs,
    int2* __restrict__ rowp, unsigned short* __restrict__ sorted_src,
    unsigned short* __restrict__ perm)
{
    __shared__ int deg[256];
    __shared__ int scn[256];
    __shared__ int cur[256];
    __shared__ int hist2[64];
    __shared__ int scn2[64];
    __shared__ int cur2[64];
    const int n0 = b * BW;
    const int n1 = (n0 + BW < NN) ? n0 + BW : NN;
    const int nloc = n1 - n0;
    const int tid = threadIdx.x;
    const int mycnt = bcursor[b];
    const unsigned* seg = pairs + (size_t)b * CAP;
    const int base = b * SCAP;

    deg[tid] = 0;
    if (tid < 64) hist2[tid] = 0;
    __syncthreads();
    for (int i = tid; i < mycnt; i += 256)
        atomicAdd(&deg[(seg[i] >> 16) & 0xff], 1);
    __syncthreads();

    const int pv = (deg[tid] + 3) & ~3;            // padded degree
    int it = pv >> 2; if (it > 63) it = 63;
    it = 63 - it;                                  // descending-degree key (LPT)
    scn[tid] = pv;
    if (tid < nloc) atomicAdd(&hist2[it], 1);
    __syncthreads();
    for (int off = 1; off < 256; off <<= 1) {
        int t = (tid >= off) ? scn[tid - off] : 0;
        __syncthreads();
        scn[tid] += t;
        __syncthreads();
    }
    if (tid < 64) scn2[tid] = hist2[tid];
    __syncthreads();
    for (int off = 1; off < 64; off <<= 1) {
        int t = (tid >= off && tid < 64) ? scn2[tid - off] : 0;
        __syncthreads();
        if (tid < 64) scn2[tid] += t;
        __syncthreads();
    }
    if (tid < 64) cur2[tid] = scn2[tid] - hist2[tid];
    __syncthreads();

    const int totalp = scn[255];
    const int pexcl  = scn[tid] - pv;
    cur[tid] = base + pexcl;
    if (tid < nloc) {
        int rank = atomicAdd(&cur2[it], 1);        // degree-sorted local rank
        perm[n0 + rank] = (unsigned short)(n0 + tid);
        rowp[n0 + rank] = make_int2(base + pexcl, base + pexcl + pv);
    }
    __syncthreads();

    int lim = totalp + 8; if (lim > SCAP) lim = SCAP;
    for (int i = tid; i < lim; i += 256)
        sorted_src[base + i] = (unsigned short)NN;
    if (b == NBUCK - 1 && tid < 8)
        sorted_src[NBUCK * SCAP + tid] = (unsigned short)NN;
    __syncthreads();
    for (int i = tid; i < mycnt; i += 256) {
        unsigned p = seg[i];
        int pos = atomicAdd(&cur[(p >> 16) & 0xff], 1);
        sorted_src[pos] = (unsigned short)(p & 0xffff);
    }
}

// ---------------------------------------------------------------------------
// Overlap dispatches: [bin || gemm1 first half], [sort || gemm1 second half]
// ---------------------------------------------------------------------------
__global__ __launch_bounds__(256) void bin_gemm(
    const int* __restrict__ ei, int* __restrict__ bcursor,
    unsigned* __restrict__ pairs,
    const float* __restrict__ x, const unsigned short* __restrict__ Wt,
    const float* __restrict__ a_s, const float* __restrict__ a_d,
    unsigned short* __restrict__ hout, float* __restrict__ asrc,
    float* __restrict__ adst)
{
    if (blockIdx.x < NB_B)
        bin_body(blockIdx.x, ei, bcursor, pairs);
    else
        gemm_body<8, 4, true, 32>(blockIdx.x - NB_B, x, Wt, a_s, a_d,
                                  hout, asrc, adst);
}

__global__ __launch_bounds__(256) void sort_gemm(
    const int* __restrict__ bcursor, const unsigned* __restrict__ pairs,
    int2* __restrict__ rowp, unsigned short* __restrict__ sorted_src,
    unsigned short* __restrict__ perm,
    const float* __restrict__ x, const unsigned short* __restrict__ Wt,
    const float* __restrict__ a_s, const float* __restrict__ a_d,
    unsigned short* __restrict__ hout, float* __restrict__ asrc,
    float* __restrict__ adst)
{
    if (blockIdx.x < NBUCK)
        sort_body(blockIdx.x, bcursor, pairs, rowp, sorted_src, perm);
    else
        gemm_body<8, 4, true, 32>(blockIdx.x - NBUCK + G1A, x, Wt, a_s, a_d,
                                  hout, asrc, adst);
}

// standalone GEMM wrappers (layers 2 and 3)
__global__ __launch_bounds__(256) void gemm_l2(
    const unsigned short* __restrict__ hin, const unsigned short* __restrict__ Wt,
    const float* __restrict__ a_s, const float* __restrict__ a_d,
    unsigned short* __restrict__ hout, float* __restrict__ asrc,
    float* __restrict__ adst)
{
    gemm_body<8, 4, false, 32>(blockIdx.x, hin, Wt, a_s, a_d, hout, asrc, adst);
}

__global__ __launch_bounds__(256) void gemm_l3(
    const unsigned short* __restrict__ hin, const unsigned short* __restrict__ Wt,
    const float* __restrict__ a_s, const float* __restrict__ a_d,
    unsigned short* __restrict__ hout, float* __restrict__ asrc,
    float* __restrict__ adst)
{
    gemm_body<2, 1, false, 0>(blockIdx.x, hin, Wt, a_s, a_d, hout, asrc, adst);
}

// ---------------------------------------------------------------------------
// Aggregation core over [b0, e0): padded mask-free 4-deep batches, index
// prefetch; pads -> sentinel node NN. asrc pre-scaled by 1/ln2:
// w = v_exp_f32(leaky(a+d)) == exp(orig). hp points at this lane's 8-ch
// slice within a 64-B (32-ch) row; row stride 16 uints.
// ---------------------------------------------------------------------------
template<int NH>
__device__ inline void aggr_range32(
    int b0, int e0, int head, float ad,
    const unsigned short* __restrict__ sorted_src,
    const uint* __restrict__ hp,
    const float* __restrict__ asrc,
    float num[8], float& den)
{
    ushort4 sv = *(const ushort4*)&sorted_src[b0];
    for (int i = b0; i < e0; i += 4) {
        ushort4 nx = *(const ushort4*)&sorted_src[i + 4];   // slack sentinel-filled
        const int s[4] = {sv.x, sv.y, sv.z, sv.w};
        float a[4];
        uint4 Hv[4];
        #pragma unroll
        for (int j = 0; j < 4; ++j) a[j] = asrc[s[j] * NH + head];
        #pragma unroll
        for (int j = 0; j < 4; ++j)
            Hv[j] = *(const uint4*)&hp[(long long)s[j] * 16];
        #pragma unroll
        for (int j = 0; j < 4; ++j) {
            float l = a[j] + ad; l = l > 0.f ? l : 0.2f * l;
            float w;
            asm("v_exp_f32 %0, %1" : "=v"(w) : "v"(l));     // 2^l
            den += w;
            num[0] = fmaf(w, bflo(Hv[j].x), num[0]); num[1] = fmaf(w, bfhi(Hv[j].x), num[1]);
            num[2] = fmaf(w, bflo(Hv[j].y), num[2]); num[3] = fmaf(w, bfhi(Hv[j].y), num[3]);
            num[4] = fmaf(w, bflo(Hv[j].z), num[4]); num[5] = fmaf(w, bfhi(Hv[j].z), num[5]);
            num[6] = fmaf(w, bflo(Hv[j].w), num[6]); num[7] = fmaf(w, bfhi(Hv[j].w), num[7]);
        }
        sv = nx;
    }
}

// ---------------------------------------------------------------------------
// CHANNEL-SLICED aggregation (128-ch layers): block (g = blockIdx%4,
// ib = blockIdx/4) aggregates ONLY group g's 32 channels (== head g) for
// 64 nodes, 4 lanes/node. XCD x (= blockIdx%8) always sees g = x%4, so each
// XCD touches one 3.2 MB slice of h — L2-resident; compulsory HBM fetch
// ~8x3.2 -> counted once per pair of XCDs. 64-B rows = 1 line/edge/group,
// 4 total lines/edge — same transaction count as r8's flat 256-B rows.
// Output non-temporal (protect slice residency).
// ---------------------------------------------------------------------------
__global__ __launch_bounds__(256) void aggr_slice(
    const unsigned short* __restrict__ perm,
    const int2* __restrict__ rowp, const unsigned short* __restrict__ sorted_src,
    const unsigned short* __restrict__ hin,      // [4][NN+1][32] bf16
    const float* __restrict__ asrc, const float* __restrict__ adst,
    const float* __restrict__ bias,
    unsigned short* __restrict__ outg)           // [4][NN+1][32] bf16
{
    const int g   = blockIdx.x & 3;              // channel group == head
    const int ib  = blockIdx.x >> 2;
    const int tid = threadIdx.x;
    const int ln  = tid >> 2;                    // local node 0..63
    const int c8  = tid & 3;                     // 8-ch quarter of the group
    const int rk  = ib * 64 + ln;
    if (rk >= NN) return;
    const int d    = perm[rk];
    const float ad = adst[d * 4 + g];
    const uint* hp = (const uint*)hin + (size_t)g * (NN + 1) * 16 + c8 * 4;
    const int2 be  = rowp[rk];

    float num[8] = {};
    float den = 0.f;
    aggr_range32<4>(be.x, be.y, g, ad, sorted_src, hp, asrc, num, den);

    float inv = 1.f / (den + 1e-16f);
    const int cc = g * 32 + c8 * 8;              // absolute channel base
    float v[8];
    #pragma unroll
    for (int j = 0; j < 8; ++j) {
        v[j] = num[j] * inv + bias[cc + j];
        v[j] = v[j] > 0.f ? v[j] : expm1f(v[j]);      // ELU
    }
    u32x4 u;
    u[0] = bf16rne(v[0]) | (bf16rne(v[1]) << 16);
    u[1] = bf16rne(v[2]) | (bf16rne(v[3]) << 16);
    u[2] = bf16rne(v[4]) | (bf16rne(v[5]) << 16);
    u[3] = bf16rne(v[6]) | (bf16rne(v[7]) << 16);
    __builtin_nontemporal_store(
        u, (u32x4*)(outg + ((size_t)g * (NN + 1) + d) * 32 + c8 * 8));
}

// ---------------------------------------------------------------------------
// Final aggregation (layer 3, flat H3, fp32 out): 4 lanes/node, 8 ch/lane.
// ---------------------------------------------------------------------------
__global__ __launch_bounds__(256) void aggr_final(
    const unsigned short* __restrict__ perm,
    const int2* __restrict__ rowp, const unsigned short* __restrict__ sorted_src,
    const unsigned short* __restrict__ hin,      // flat (NN+1)*32 bf16
    const float* __restrict__ asrc, const float* __restrict__ adst,
    const float* __restrict__ bias, float* __restrict__ out)
{
    int t = blockIdx.x * 256 + threadIdx.x;
    int rk = t >> 2;
    int lc = t & 3;
    if (rk >= NN) return;
    const int d  = perm[rk];
    const float ad = adst[d];
    const uint* hp = (const uint*)hin + lc * 4;
    const int2 be  = rowp[rk];

    float num[8] = {};
    float den = 0.f;
    aggr_range32<1>(be.x, be.y, 0, ad, sorted_src, hp, asrc, num, den);

    float inv = 1.f / (den + 1e-16f);
    const int cc = lc * 8;
    float v[8];
    #pragma unroll
    for (int j = 0; j < 8; ++j) v[j] = num[j] * inv + bias[cc + j];
    float* op = out + (long long)d * 32 + cc;
    *(float4*)(op)     = make_float4(v[0], v[1], v[2], v[3]);
    *(float4*)(op + 4) = make_float4(v[4], v[5], v[6], v[7]);
}

// ---------------------------------------------------------------------------
extern "C" void kernel_launch(void* const* d_in, const int* in_sizes, int n_in,
                              void* d_out, int out_size, void* d_ws, size_t ws_size,
                              hipStream_t stream)
{
    const float* x   = (const float*)d_in[0];
    const int*   ei  = (const int*)  d_in[1];
    const float* W1  = (const float*)d_in[2];
    const float* as1 = (const float*)d_in[3];
    const float* ad1 = (const float*)d_in[4];
    const float* b1  = (const float*)d_in[5];
    const float* W2  = (const float*)d_in[6];
    const float* as2 = (const float*)d_in[7];
    const float* ad2 = (const float*)d_in[8];
    const float* b2  = (const float*)d_in[9];
    const float* W3  = (const float*)d_in[10];
    const float* as3 = (const float*)d_in[11];
    const float* ad3 = (const float*)d_in[12];
    const float* b3  = (const float*)d_in[13];
    float* out = (float*)d_out;

    // workspace: HA/HB = (NN+1)*128 bf16 grouped [4][NN+1][32]; H3 flat.
    // gemm1: x -> HA; aggr1: HA -> HB; gemm2: HB -> HA; aggr2: HA -> HB;
    // gemm3: HB -> H3; aggr3: H3 -> out.
    unsigned short* HA  = (unsigned short*)d_ws;          // (N+1)*128 bf16
    unsigned short* HB  = HA + (size_t)(NN + 1) * 128;    // (N+1)*128 bf16
    unsigned short* H3  = HB + (size_t)(NN + 1) * 128;    // (N+1)*32 bf16
    unsigned short* W1t = H3 + (size_t)(NN + 1) * 32;     // 128*128 bf16
    unsigned short* W2t = W1t + 128 * 128;
    unsigned short* W3t = W2t + 128 * 128;                // 32*128
    float* AS1 = (float*)(W3t + 32 * 128);                // (N+1)*4
    float* AD1 = AS1 + (size_t)(NN + 1) * 4;              // N*4
    float* AS2 = AD1 + (size_t)NN * 4;                    // (N+1)*4
    float* AD2 = AS2 + (size_t)(NN + 1) * 4;              // N*4
    float* AS3 = AD2 + (size_t)NN * 4;                    // (N+1)
    float* AD3 = AS3 + (size_t)(NN + 1);                  // N
    int2* rowp = (int2*)(AD3 + NN);                       // NN int2 (rank-indexed)
    unsigned short* sorted = (unsigned short*)(rowp + NN);         // NBUCK*SCAP+8
    int* bcursor = (int*)(sorted + (size_t)NBUCK * SCAP + 8);      // NBUCK
    unsigned short* perm = (unsigned short*)(bcursor + NBUCK);     // NN u16
    size_t off = ((size_t)(perm + NN) - (size_t)d_ws + 15) & ~(size_t)15;
    unsigned* pairs = (unsigned*)((char*)d_ws + off);     // NBUCK*CAP u32 (4 MB)

    const int gCvtW  = (4608 + 255) / 256;               // 18
    const int gBinG  = NB_B + G1A;                       // 416 + 391
    const int gSortG = NBUCK + (G1ALL - G1A);            // 256 + 391
    const int gGemm  = G1ALL;                            // 782
    const int gAggrS = 4 * ((NN + 63) / 64);             // 3128
    const int gAggrF = (NN * 4 + 255) / 256;             // 782

    // 1) weights + sentinels + cursor zeroing
    cvt_weights<<<gCvtW, 256, 0, stream>>>(W1, W2, W3, W1t, W2t, W3t, bcursor,
                                           AS1, AS2, AS3, HA, HB, H3);
    // 2) edge binning || layer-1 GEMM (first half) -> HA grouped
    bin_gemm<<<gBinG, 256, 0, stream>>>(ei, bcursor, pairs,
                                        x, W1t, as1, ad1, HA, AS1, AD1);
    // 3) CSR sort (+LPT ranks) || layer-1 GEMM (second half)
    sort_gemm<<<gSortG, 256, 0, stream>>>(bcursor, pairs, rowp, sorted, perm,
                                          x, W1t, as1, ad1, HA, AS1, AD1);
    // 4) aggr layer 1 (channel-sliced, XCD-affine): HA -> HB
    aggr_slice<<<gAggrS, 256, 0, stream>>>(
        perm, rowp, sorted, HA, AS1, AD1, b1, HB);
    // 5) GEMM layer 2: HB -> HA (+AS2/AD2)
    gemm_l2<<<gGemm, 256, 0, stream>>>(HB, W2t, as2, ad2, HA, AS2, AD2);
    // 6) aggr layer 2: HA -> HB
    aggr_slice<<<gAggrS, 256, 0, stream>>>(
        perm, rowp, sorted, HA, AS2, AD2, b2, HB);
    // 7) GEMM layer 3: HB -> H3 flat (+AS3/AD3)
    gemm_l3<<<gGemm, 256, 0, stream>>>(HB, W3t, as3, ad3, H3, AS3, AD3);
    // 8) final aggr (flat): H3 -> out
    aggr_final<<<gAggrF, 256, 0, stream>>>(
        perm, rowp, sorted, H3, AS3, AD3, b3, out);
}

// Round 15
// 253.388 us; speedup vs baseline: 1.3862x; 1.1392x over previous
//
#include <hip/hip_runtime.h>
#include <cmath>

constexpr int NN  = 50000;          // nodes
constexpr int EE  = 800000;         // raw edges
constexpr int E2C = EE + NN;        // edges incl. self loops = 850000

// bucketed counting sort params
constexpr int NBUCK = 256;          // dst buckets
constexpr int BW    = 196;          // bucket width: 196*256 = 50176 >= NN
constexpr int EPT   = 8;            // edges per thread (bin)
constexpr int CH    = 256 * EPT;    // 2048 edges per block
constexpr int NB_B  = (E2C + CH - 1) / CH;  // 416 blocks
constexpr int CAP   = 4096;         // per-bucket pairs capacity
constexpr int SCAP  = 5120;         // per-bucket padded sorted capacity
constexpr int G1ALL = (NN + 63) / 64;       // 782 gemm1 blocks
constexpr int G1A   = 391;                  // gemm1 blocks co-run with bin

constexpr float RLN2 = 1.44269504088896340736f;   // 1/ln2

using bf16x8 = __attribute__((ext_vector_type(8))) short;
using f32x4  = __attribute__((ext_vector_type(4))) float;

// bf16 helpers (storage bf16, math fp32)
__device__ inline unsigned bf16rne(float f) {
    unsigned u = __builtin_bit_cast(unsigned, f);
    return (u + 0x7fffu + ((u >> 16) & 1u)) >> 16;     // round-nearest-even
}
__device__ inline float bflo(unsigned u) { return __builtin_bit_cast(float, u << 16); }
__device__ inline float bfhi(unsigned u) { return __builtin_bit_cast(float, u & 0xffff0000u); }

// ---------------------------------------------------------------------------
// W[k,c] fp32 -> Wt[c,k] bf16 (all three), + zero bcursor, + write alpha
// sentinels (-1e30 at node NN) and zero h sentinel rows.
// ---------------------------------------------------------------------------
__global__ __launch_bounds__(256) void cvt_weights(
    const float* __restrict__ W1, const float* __restrict__ W2,
    const float* __restrict__ W3,
    unsigned short* __restrict__ W1t, unsigned short* __restrict__ W2t,
    unsigned short* __restrict__ W3t, int* __restrict__ bcursor,
    float* __restrict__ AS1, float* __restrict__ AS2, float* __restrict__ AS3,
    unsigned short* __restrict__ H1, unsigned short* __restrict__ H2,
    unsigned short* __restrict__ H3)
{
    int g = blockIdx.x * 256 + threadIdx.x;
    if (g < NBUCK) bcursor[g] = 0;
    if (g < 4) { AS1[NN * 4 + g] = -1e30f; AS2[NN * 4 + g] = -1e30f; }
    if (g == 4) AS3[NN] = -1e30f;
    if (g < 128) { H1[(size_t)NN * 128 + g] = 0; H2[(size_t)NN * 128 + g] = 0; }
    if (g < 32)  H3[(size_t)NN * 32 + g] = 0;

    const float* W; unsigned short* Wt; int cols;
    if (g < 2048)      { W = W1; Wt = W1t; cols = 128; }
    else if (g < 4096) { W = W2; Wt = W2t; cols = 128; g -= 2048; }
    else if (g < 4608) { W = W3; Wt = W3t; cols = 32;  g -= 4096; }
    else return;
    int c  = g / 16;
    int k8 = (g % 16) * 8;
    unsigned up[4];
    #pragma unroll
    for (int j = 0; j < 4; ++j) {
        float a = W[(k8 + 2 * j) * cols + c];
        float b = W[(k8 + 2 * j + 1) * cols + c];
        up[j] = bf16rne(a) | (bf16rne(b) << 16);
    }
    uint4 u; u.x = up[0]; u.y = up[1]; u.z = up[2]; u.w = up[3];
    *(uint4*)(Wt + c * 128 + k8) = u;
}

// ---------------------------------------------------------------------------
// Layer-1 MFMA GEMM body (64 nodes per bid) + fused alpha dots
// (alpha pre-scaled by 1/ln2 for native v_exp_f32 in aggr).
// ---------------------------------------------------------------------------
template<int NT, int NH, bool F32IN>
__device__ inline void gemm_body(
    int bid, const void* __restrict__ inv, const unsigned short* __restrict__ Wt,
    const float* __restrict__ a_s, const float* __restrict__ a_d,
    unsigned short* __restrict__ hout, float* __restrict__ asrc,
    float* __restrict__ adst)
{
    constexpr int COLS = NT * 16;
    constexpr int TPH  = NT / NH;
    const int lane = threadIdx.x & 63;
    const int wave = threadIdx.x >> 6;
    const int m    = lane & 15;
    const int quad = lane >> 4;
    const int n0   = bid * 64 + wave * 16;

    int arow = n0 + m; if (arow >= NN) arow = NN - 1;

    f32x4 acc[NT] = {};
    #pragma unroll
    for (int kq = 0; kq < 4; ++kq) {
        bf16x8 a;
        if constexpr (F32IN) {
            const float* ap = (const float*)inv + (long long)arow * 128 + quad * 8 + kq * 32;
            float4 v0 = *(const float4*)ap;
            float4 v1 = *(const float4*)(ap + 4);
            a[0] = (short)bf16rne(v0.x); a[1] = (short)bf16rne(v0.y);
            a[2] = (short)bf16rne(v0.z); a[3] = (short)bf16rne(v0.w);
            a[4] = (short)bf16rne(v1.x); a[5] = (short)bf16rne(v1.y);
            a[6] = (short)bf16rne(v1.z); a[7] = (short)bf16rne(v1.w);
        } else {
            a = *(const bf16x8*)((const unsigned short*)inv
                    + (long long)arow * 128 + quad * 8 + kq * 32);
        }
        #pragma unroll
        for (int t = 0; t < NT; ++t) {
            bf16x8 b = *(const bf16x8*)(Wt + (t * 16 + m) * 128 + kq * 32 + quad * 8);
            acc[t] = __builtin_amdgcn_mfma_f32_16x16x32_bf16(a, b, acc[t], 0, 0, 0);
        }
    }

    #pragma unroll
    for (int r = 0; r < 4; ++r) {
        int node = n0 + quad * 4 + r;
        if (node < NN) {
            #pragma unroll
            for (int t = 0; t < NT; ++t)
                hout[(long long)node * COLS + t * 16 + m] =
                    (unsigned short)bf16rne(acc[t][r]);
        }
    }

    float asv[NT], adv[NT];
    #pragma unroll
    for (int t = 0; t < NT; ++t) {
        asv[t] = a_s[t * 16 + m] * RLN2;
        adv[t] = a_d[t * 16 + m] * RLN2;
    }

    #pragma unroll
    for (int r = 0; r < 4; ++r) {
        const int node = n0 + quad * 4 + r;
        #pragma unroll
        for (int hh = 0; hh < NH; ++hh) {
            float ps = 0.f, pd = 0.f;
            #pragma unroll
            for (int q = 0; q < TPH; ++q) {
                int t = hh * TPH + q;
                ps = fmaf(acc[t][r], asv[t], ps);
                pd = fmaf(acc[t][r], adv[t], pd);
            }
            #pragma unroll
            for (int off = 8; off > 0; off >>= 1) {
                ps += __shfl_down(ps, off, 16);
                pd += __shfl_down(pd, off, 16);
            }
            if (m == 0 && node < NN) {
                asrc[node * NH + hh] = ps;
                adst[node * NH + hh] = pd;
            }
        }
    }
}

// ---------------------------------------------------------------------------
// CSR build bodies. Record: src:16 | dlocal:8 | bucket:8.
// ---------------------------------------------------------------------------
__device__ inline void bin_body(
    int bid, const int* __restrict__ ei, int* __restrict__ bcursor,
    unsigned* __restrict__ pairs)
{
    __shared__ int cnt[NBUCK];
    __shared__ int scanex[NBUCK];
    __shared__ int base[NBUCK];
    __shared__ int cur[NBUCK];
    __shared__ unsigned stage[CH];       // 8 KB

    const int tid = threadIdx.x;
    const long long e0 = (long long)bid * CH;
    cnt[tid] = 0;
    __syncthreads();

    unsigned rec[EPT]; int bk[EPT];
    #pragma unroll
    for (int j = 0; j < EPT; ++j) {
        long long e = e0 + tid + j * 256;
        bool valid = e < E2C;
        int ss = 0, dd = 0;
        if (valid) {
            if (e < EE) { ss = ei[e]; dd = ei[EE + e]; }
            else        { ss = dd = (int)(e - EE); }
        }
        int b = dd / BW;
        bk[j]  = valid ? b : -1;
        rec[j] = (unsigned)ss | ((unsigned)(dd - b * BW) << 16) | ((unsigned)b << 24);
        if (valid) atomicAdd(&cnt[b], 1);
    }
    __syncthreads();

    const int myc = cnt[tid];
    scanex[tid] = myc;
    __syncthreads();
    for (int off = 1; off < NBUCK; off <<= 1) {
        int t = (tid >= off) ? scanex[tid - off] : 0;
        __syncthreads();
        scanex[tid] += t;
        __syncthreads();
    }
    int excl = scanex[tid] - myc;
    __syncthreads();
    scanex[tid] = excl;
    cur[tid]    = excl;
    base[tid]   = atomicAdd(&bcursor[tid], myc);
    __syncthreads();

    #pragma unroll
    for (int j = 0; j < EPT; ++j) {
        if (bk[j] >= 0) {
            int p = atomicAdd(&cur[bk[j]], 1);
            stage[p] = rec[j];
        }
    }
    __syncthreads();

    const int total = (e0 + CH <= E2C) ? CH : (int)(E2C - e0);
    for (int j = tid; j < total; j += 256) {
        unsigned p = stage[j];
        int b = (int)(p >> 24);
        pairs[(size_t)b * CAP + base[b] + (j - scanex[b])] = p;
    }
}

// sort + degree-rank: perm[rank]=node, rowp[rank]=(beg,end). Ranks sorted by
// DESCENDING padded degree (LPT: long blocks launch first, short blocks fill
// the drain tail), uniform within each 16-rank fused block.
__device__ inline void sort_body(
    int b, const int* __restrict__ bcursor, const unsigned* __restrict__ pairs,
    int2* __restrict__ rowp, unsigned short* __restrict__ sorted_src,
    unsigned short* __restrict__ perm)
{
    __shared__ int deg[256];
    __shared__ int scn[256];
    __shared__ int cur[256];
    __shared__ int hist2[64];
    __shared__ int scn2[64];
    __shared__ int cur2[64];
    const int n0 = b * BW;
    const int n1 = (n0 + BW < NN) ? n0 + BW : NN;
    const int nloc = n1 - n0;
    const int tid = threadIdx.x;
    const int mycnt = bcursor[b];
    const unsigned* seg = pairs + (size_t)b * CAP;
    const int base = b * SCAP;

    deg[tid] = 0;
    if (tid < 64) hist2[tid] = 0;
    __syncthreads();
    for (int i = tid; i < mycnt; i += 256)
        atomicAdd(&deg[(seg[i] >> 16) & 0xff], 1);
    __syncthreads();

    const int pv = (deg[tid] + 3) & ~3;            // padded degree
    int it = pv >> 2; if (it > 63) it = 63;
    it = 63 - it;                                  // descending-degree key (LPT)
    scn[tid] = pv;
    if (tid < nloc) atomicAdd(&hist2[it], 1);
    __syncthreads();
    for (int off = 1; off < 256; off <<= 1) {
        int t = (tid >= off) ? scn[tid - off] : 0;
        __syncthreads();
        scn[tid] += t;
        __syncthreads();
    }
    if (tid < 64) scn2[tid] = hist2[tid];
    __syncthreads();
    for (int off = 1; off < 64; off <<= 1) {
        int t = (tid >= off && tid < 64) ? scn2[tid - off] : 0;
        __syncthreads();
        if (tid < 64) scn2[tid] += t;
        __syncthreads();
    }
    if (tid < 64) cur2[tid] = scn2[tid] - hist2[tid];
    __syncthreads();

    const int totalp = scn[255];
    const int pexcl  = scn[tid] - pv;
    cur[tid] = base + pexcl;
    if (tid < nloc) {
        int rank = atomicAdd(&cur2[it], 1);        // degree-sorted local rank
        perm[n0 + rank] = (unsigned short)(n0 + tid);
        rowp[n0 + rank] = make_int2(base + pexcl, base + pexcl + pv);
    }
    __syncthreads();

    int lim = totalp + 8; if (lim > SCAP) lim = SCAP;
    for (int i = tid; i < lim; i += 256)
        sorted_src[base + i] = (unsigned short)NN;
    if (b == NBUCK - 1 && tid < 8)
        sorted_src[NBUCK * SCAP + tid] = (unsigned short)NN;
    __syncthreads();
    for (int i = tid; i < mycnt; i += 256) {
        unsigned p = seg[i];
        int pos = atomicAdd(&cur[(p >> 16) & 0xff], 1);
        sorted_src[pos] = (unsigned short)(p & 0xffff);
    }
}

// ---------------------------------------------------------------------------
// Overlap dispatches: [bin || gemm1 first half], [sort || gemm1 second half]
// ---------------------------------------------------------------------------
__global__ __launch_bounds__(256) void bin_gemm(
    const int* __restrict__ ei, int* __restrict__ bcursor,
    unsigned* __restrict__ pairs,
    const float* __restrict__ x, const unsigned short* __restrict__ Wt,
    const float* __restrict__ a_s, const float* __restrict__ a_d,
    unsigned short* __restrict__ hout, float* __restrict__ asrc,
    float* __restrict__ adst)
{
    if (blockIdx.x < NB_B)
        bin_body(blockIdx.x, ei, bcursor, pairs);
    else
        gemm_body<8, 4, true>(blockIdx.x - NB_B, x, Wt, a_s, a_d, hout, asrc, adst);
}

__global__ __launch_bounds__(256) void sort_gemm(
    const int* __restrict__ bcursor, const unsigned* __restrict__ pairs,
    int2* __restrict__ rowp, unsigned short* __restrict__ sorted_src,
    unsigned short* __restrict__ perm,
    const float* __restrict__ x, const unsigned short* __restrict__ Wt,
    const float* __restrict__ a_s, const float* __restrict__ a_d,
    unsigned short* __restrict__ hout, float* __restrict__ asrc,
    float* __restrict__ adst)
{
    if (blockIdx.x < NBUCK)
        sort_body(blockIdx.x, bcursor, pairs, rowp, sorted_src, perm);
    else
        gemm_body<8, 4, true>(blockIdx.x - NBUCK + G1A, x, Wt, a_s, a_d,
                              hout, asrc, adst);
}

// ---------------------------------------------------------------------------
// Per-node-channel-group CSR aggregation core over [b0, e0): padded
// mask-free 4-deep batches, index prefetch; pads -> sentinel node NN.
// asrc/adst are pre-scaled by 1/ln2: w = v_exp_f32(leaky(a+d)) == exp(orig).
// Accumulates into num[8]/den (caller-owned; may be partial).
// ---------------------------------------------------------------------------
template<int COLS, int NH>
__device__ inline void aggr_range(
    int b0, int e0, int head, float ad,
    const unsigned short* __restrict__ sorted_src,
    const uint* __restrict__ hp,
    const float* __restrict__ asrc,
    float num[8], float& den)
{
    constexpr int USTR = COLS / 2;            // uints per h row
    ushort4 sv = *(const ushort4*)&sorted_src[b0];
    for (int i = b0; i < e0; i += 4) {
        ushort4 nx = *(const ushort4*)&sorted_src[i + 4];   // slack sentinel-filled
        const int s[4] = {sv.x, sv.y, sv.z, sv.w};
        float a[4];
        uint4 Hv[4];
        #pragma unroll
        for (int j = 0; j < 4; ++j) a[j] = asrc[s[j] * NH + head];
        #pragma unroll
        for (int j = 0; j < 4; ++j)
            Hv[j] = *(const uint4*)&hp[(long long)s[j] * USTR];
        #pragma unroll
        for (int j = 0; j < 4; ++j) {
            float l = a[j] + ad; l = l > 0.f ? l : 0.2f * l;
            float w;
            asm("v_exp_f32 %0, %1" : "=v"(w) : "v"(l));     // 2^l
            den += w;
            num[0] = fmaf(w, bflo(Hv[j].x), num[0]); num[1] = fmaf(w, bfhi(Hv[j].x), num[1]);
            num[2] = fmaf(w, bflo(Hv[j].y), num[2]); num[3] = fmaf(w, bfhi(Hv[j].y), num[3]);
            num[4] = fmaf(w, bflo(Hv[j].z), num[4]); num[5] = fmaf(w, bfhi(Hv[j].z), num[5]);
            num[6] = fmaf(w, bflo(Hv[j].w), num[6]); num[7] = fmaf(w, bfhi(Hv[j].w), num[7]);
        }
        sv = nx;
    }
}

// ---------------------------------------------------------------------------
// FUSED aggregation + next-layer mini-GEMM, 512 threads / block:
// 16 ranks x 16 lanes x 2 EDGE-SPLITS. Split-1 partials combine through
// LDS, then waves 0-3 run the mini-GEMM.
// ---------------------------------------------------------------------------
template<int NT_OUT, int NH_OUT>
__global__ __launch_bounds__(512) void aggr_gemm(
    const unsigned short* __restrict__ perm,
    const int2* __restrict__ rowp, const unsigned short* __restrict__ sorted_src,
    const unsigned short* __restrict__ hin,
    const float* __restrict__ asrc_in, const float* __restrict__ adst_in,
    const float* __restrict__ bias,
    const unsigned short* __restrict__ Wt,
    const float* __restrict__ a_s, const float* __restrict__ a_d,
    unsigned short* __restrict__ hout, float* __restrict__ asrc_out,
    float* __restrict__ adst_out)
{
    __shared__ unsigned short lds_h[16 * 128];   // 4 KB
    __shared__ int lds_node[16];
    __shared__ float lds_p[256][9];              // 9 KB split-1 partials
    const int tid   = threadIdx.x;
    const int split = tid >> 8;
    const int t8    = tid & 255;
    const int row   = t8 >> 4;                   // local rank 0..15
    const int lc    = t8 & 15;
    const int rk    = blockIdx.x * 16 + row;     // grid exact: rk < NN
    const int d     = perm[rk];
    if (split == 0 && lc == 0) lds_node[row] = d;

    const int cc   = lc * 8;
    const int head = cc / 32;
    const float ad = adst_in[d * 4 + head];
    const uint* hp = (const uint*)hin + cc / 2;

    const int2 be = rowp[rk];
    const int beg = be.x, end = be.y;            // 4-aligned
    const int half = (end - beg) >> 1;
    const int mid  = beg + ((half + 3) & ~3);    // beg <= mid <= end, 4-aligned
    const int b0 = split ? mid : beg;
    const int e0 = split ? end : mid;

    float num[8] = {};
    float den = 0.f;
    aggr_range<128, 4>(b0, e0, head, ad, sorted_src, hp, asrc_in, num, den);

    if (split) {
        #pragma unroll
        for (int j = 0; j < 8; ++j) lds_p[t8][j] = num[j];
        lds_p[t8][8] = den;
    }
    __syncthreads();

    if (!split) {
        #pragma unroll
        for (int j = 0; j < 8; ++j) num[j] += lds_p[t8][j];
        den += lds_p[t8][8];
        float inv = 1.f / (den + 1e-16f);
        float v[8];
        #pragma unroll
        for (int j = 0; j < 8; ++j) {
            v[j] = num[j] * inv + bias[cc + j];
            v[j] = v[j] > 0.f ? v[j] : expm1f(v[j]);      // ELU
        }
        // stage post-ELU output tile to LDS as bf16, swizzled
        uint4 u;
        u.x = bf16rne(v[0]) | (bf16rne(v[1]) << 16);
        u.y = bf16rne(v[2]) | (bf16rne(v[3]) << 16);
        u.z = bf16rne(v[4]) | (bf16rne(v[5]) << 16);
        u.w = bf16rne(v[6]) | (bf16rne(v[7]) << 16);
        *(uint4*)((char*)lds_h + row * 256 + ((lc * 16) ^ ((row & 7) << 4))) = u;
    }
    __syncthreads();
    if (split) return;

    // ---- mini-GEMM: 16 permuted rows x 128k @ Wt (waves 0-3) ----
    const int lane = t8 & 63;
    const int wave = t8 >> 6;
    const int m    = lane & 15;
    const int quad = lane >> 4;
    int t0;
    if constexpr (NT_OUT == 8) t0 = wave * 2;
    else { if (wave != 0) return; t0 = 0; }

    f32x4 acc[2] = {};
    #pragma unroll
    for (int kq = 0; kq < 4; ++kq) {
        int colb = (quad * 16 + kq * 64) ^ ((m & 7) << 4);
        bf16x8 a = *(const bf16x8*)((const char*)lds_h + m * 256 + colb);
        #pragma unroll
        for (int tt = 0; tt < 2; ++tt) {
            bf16x8 b = *(const bf16x8*)(Wt + ((t0 + tt) * 16 + m) * 128
                                        + kq * 32 + quad * 8);
            acc[tt] = __builtin_amdgcn_mfma_f32_16x16x32_bf16(a, b, acc[tt], 0, 0, 0);
        }
    }

    constexpr int COLS_OUT = NT_OUT * 16;
    const int headw = t0 / (NT_OUT / NH_OUT);
    float asv[2], adv[2];
    #pragma unroll
    for (int tt = 0; tt < 2; ++tt) {
        asv[tt] = a_s[(t0 + tt) * 16 + m] * RLN2;
        adv[tt] = a_d[(t0 + tt) * 16 + m] * RLN2;
    }

    #pragma unroll
    for (int r = 0; r < 4; ++r) {
        const int node = lds_node[quad * 4 + r];
        #pragma unroll
        for (int tt = 0; tt < 2; ++tt)
            hout[(long long)node * COLS_OUT + (t0 + tt) * 16 + m] =
                (unsigned short)bf16rne(acc[tt][r]);
        float ps = acc[0][r] * asv[0];
        ps = fmaf(acc[1][r], asv[1], ps);
        float pd = acc[0][r] * adv[0];
        pd = fmaf(acc[1][r], adv[1], pd);
        #pragma unroll
        for (int off = 8; off > 0; off >>= 1) {
            ps += __shfl_down(ps, off, 16);
            pd += __shfl_down(pd, off, 16);
        }
        if (m == 0) {
            asrc_out[node * NH_OUT + headw] = ps;
            adst_out[node * NH_OUT + headw] = pd;
        }
    }
}

// ---------------------------------------------------------------------------
// Final standalone aggregation (layer 3): fp32 output to d_out.
// ---------------------------------------------------------------------------
template<int COLS, int NH>
__global__ __launch_bounds__(256) void aggr_final(
    const unsigned short* __restrict__ perm,
    const int2* __restrict__ rowp, const unsigned short* __restrict__ sorted_src,
    const unsigned short* __restrict__ hin,
    const float* __restrict__ asrc, const float* __restrict__ adst,
    const float* __restrict__ bias, float* __restrict__ out)
{
    constexpr int TPN = COLS / 8;
    int t = blockIdx.x * 256 + threadIdx.x;
    int rk = t / TPN;
    int lc = t % TPN;
    if (rk >= NN) return;
    const int d = perm[rk];
    const int cc = lc * 8;
    const int head = cc / 32;
    const float ad = adst[d * NH + head];
    const int2 be = rowp[rk];
    const uint* hp = (const uint*)hin + cc / 2;
    float num[8] = {};
    float den = 0.f;
    aggr_range<COLS, NH>(be.x, be.y, head, ad, sorted_src, hp, asrc, num, den);
    float inv = 1.f / (den + 1e-16f);
    float v[8];
    #pragma unroll
    for (int j = 0; j < 8; ++j) v[j] = num[j] * inv + bias[cc + j];
    float4 o0 = {v[0], v[1], v[2], v[3]};
    float4 o1 = {v[4], v[5], v[6], v[7]};
    *(float4*)&out[(long long)d * COLS + lc * 8]     = o0;
    *(float4*)&out[(long long)d * COLS + lc * 8 + 4] = o1;
}

// ---------------------------------------------------------------------------
extern "C" void kernel_launch(void* const* d_in, const int* in_sizes, int n_in,
                              void* d_out, int out_size, void* d_ws, size_t ws_size,
                              hipStream_t stream)
{
    const float* x   = (const float*)d_in[0];
    const int*   ei  = (const int*)  d_in[1];
    const float* W1  = (const float*)d_in[2];
    const float* as1 = (const float*)d_in[3];
    const float* ad1 = (const float*)d_in[4];
    const float* b1  = (const float*)d_in[5];
    const float* W2  = (const float*)d_in[6];
    const float* as2 = (const float*)d_in[7];
    const float* ad2 = (const float*)d_in[8];
    const float* b2  = (const float*)d_in[9];
    const float* W3  = (const float*)d_in[10];
    const float* as3 = (const float*)d_in[11];
    const float* ad3 = (const float*)d_in[12];
    const float* b3  = (const float*)d_in[13];
    float* out = (float*)d_out;

    // workspace layout (16B-aligned bf16 buffers first); each h has a
    // zeroed sentinel row NN.
    unsigned short* H1  = (unsigned short*)d_ws;          // (N+1)*128 bf16
    unsigned short* H2  = H1 + (size_t)(NN + 1) * 128;    // (N+1)*128 bf16
    unsigned short* H3  = H2 + (size_t)(NN + 1) * 128;    // (N+1)*32 bf16
    unsigned short* W1t = H3 + (size_t)(NN + 1) * 32;     // 128*128 bf16
    unsigned short* W2t = W1t + 128 * 128;
    unsigned short* W3t = W2t + 128 * 128;                // 32*128
    float* AS1 = (float*)(W3t + 32 * 128);                // (N+1)*4
    float* AD1 = AS1 + (size_t)(NN + 1) * 4;              // N*4
    float* AS2 = AD1 + (size_t)NN * 4;                    // (N+1)*4
    float* AD2 = AS2 + (size_t)(NN + 1) * 4;              // N*4
    float* AS3 = AD2 + (size_t)NN * 4;                    // (N+1)
    float* AD3 = AS3 + (size_t)(NN + 1);                  // N
    int2* rowp = (int2*)(AD3 + NN);                       // NN int2 (rank-indexed)
    unsigned short* sorted = (unsigned short*)(rowp + NN);         // NBUCK*SCAP+8
    int* bcursor = (int*)(sorted + (size_t)NBUCK * SCAP + 8);      // NBUCK
    unsigned short* perm = (unsigned short*)(bcursor + NBUCK);     // NN u16
    size_t off = ((size_t)(perm + NN) - (size_t)d_ws + 15) & ~(size_t)15;
    unsigned* pairs = (unsigned*)((char*)d_ws + off);     // NBUCK*CAP u32 (4 MB)

    const int gCvtW  = (4608 + 255) / 256;               // 18
    const int gBinG  = NB_B + G1A;                       // 416 + 391
    const int gSortG = NBUCK + (G1ALL - G1A);            // 256 + 391
    const int gFused = NN / 16;                          // 3125 (exact)
    const int gAggr3 = (NN * 4 + 255) / 256;             // 782

    // 1) weights + sentinels
    cvt_weights<<<gCvtW, 256, 0, stream>>>(W1, W2, W3, W1t, W2t, W3t, bcursor,
                                           AS1, AS2, AS3, H1, H2, H3);
    // 2) edge binning || layer-1 GEMM (first half)
    bin_gemm<<<gBinG, 256, 0, stream>>>(ei, bcursor, pairs,
                                        x, W1t, as1, ad1, H1, AS1, AD1);
    // 3) CSR sort (+LPT degree ranks) || layer-1 GEMM (second half)
    sort_gemm<<<gSortG, 256, 0, stream>>>(bcursor, pairs, rowp, sorted, perm,
                                          x, W1t, as1, ad1, H1, AS1, AD1);
    // 4) aggr layer 1 + GEMM layer 2 (fused, 2-way edge split, 512 thr)
    aggr_gemm<8, 4><<<gFused, 512, 0, stream>>>(
        perm, rowp, sorted, H1, AS1, AD1, b1, W2t, as2, ad2, H2, AS2, AD2);
    // 5) aggr layer 2 + GEMM layer 3 (fused)
    aggr_gemm<2, 1><<<gFused, 512, 0, stream>>>(
        perm, rowp, sorted, H2, AS2, AD2, b2, W3t, as3, ad3, H3, AS3, AD3);
    // 6) final aggr layer 3 -> fp32 output
    aggr_final<32, 1><<<gAggr3, 256, 0, stream>>>(
        perm, rowp, sorted, H3, AS3, AD3, b3, out);
}